// Round 18
// baseline (384.029 us; speedup 1.0000x reference)
//
#include <hip/hip_runtime.h>
#include <hip/hip_bf16.h>

#define N_NODES 20000
#define N_EDGES 320000
#define EBLK 64
#define NBLK 32

typedef __attribute__((ext_vector_type(8))) short short8;
typedef __attribute__((ext_vector_type(4))) float f32x4;

static __device__ __forceinline__ unsigned short f2bf(float f) {
  __hip_bfloat16 h = __float2bfloat16(f);
  union { __hip_bfloat16 h; unsigned short u; } cv; cv.h = h; return cv.u;
}

static __device__ __forceinline__ float bf2f(unsigned short u) {
  union { unsigned int u; float f; } cv; cv.u = ((unsigned int)u) << 16; return cv.f;
}

static __device__ __forceinline__ unsigned int pk2(float a, float b) {
  return (unsigned int)f2bf(a) | ((unsigned int)f2bf(b) << 16);
}

// tanh-form GELU via one v_exp_f32; max |err| vs exact-erf ~3e-3 (margin 3x+).
static __device__ __forceinline__ float gelu_f(float x) {
  float z = x * (2.3022082f + 0.1029432f * x * x);  // pre-scaled by log2(e)
  z = fminf(fmaxf(z, -30.0f), 30.0f);
  float t = exp2f(z);
  return x * t * __frcp_rn(1.0f + t);
}

// XOR swizzle for bf16 tiles (16B granule spread across rows)
#define SWZ(row, byteoff) ((byteoff) ^ (((row) & 7) << 4))
// fp32 U tile swizzle keyed off address bits
#define SWZU(b) ((b) ^ ((((b) >> 8) & 7) << 4))

// ---------------------------------------------------------------- pack + hist (fused)
__global__ void packhist_kernel(const float* __restrict__ W1m, const float* __restrict__ W2m,
                                const float* __restrict__ W1u, const float* __restrict__ W2u,
                                unsigned short* __restrict__ P1m, unsigned short* __restrict__ P2m,
                                unsigned short* __restrict__ P1u, unsigned short* __restrict__ P2u,
                                const int* __restrict__ dst, int* __restrict__ cnt) {
  if (blockIdx.x >= 1536) {
    int e = (blockIdx.x - 1536) * blockDim.x + threadIdx.x;
    atomicAdd(&cnt[dst[e]], 1);
    return;
  }
  int idx = blockIdx.x * blockDim.x + threadIdx.x;
  const float* W; unsigned short* P; int K, Nc, local;
  if (idx < 65536)        { W = W1m; P = P1m; K = 256; Nc = 256; local = idx; }
  else if (idx < 131072)  { W = W2m; P = P2m; K = 256; Nc = 256; local = idx - 65536; }
  else if (idx < 262144)  { W = W1u; P = P1u; K = 256; Nc = 512; local = idx - 131072; }
  else                    { W = W2u; P = P2u; K = 512; Nc = 256; local = idx - 262144; }
  int frag = local >> 9, wi = local & 511;
  int l = wi >> 3, i = wi & 7;
  int kf = K >> 5;
  int cf = frag / kf, t = frag % kf;
  int k = t * 32 + (l >> 4) * 8 + i;
  int n = cf * 16 + (l & 15);
  P[local] = f2bf(W[(size_t)k * Nc + n]);
}

// ---------------------------------------------------------------- prefix scan
__global__ __launch_bounds__(1024) void scan_kernel(const int* __restrict__ cnt,
                                                    int* __restrict__ rptr,
                                                    int* __restrict__ cur) {
  __shared__ int wsum[16];
  const int t = threadIdx.x;
  const int lane = t & 63, wid = t >> 6;
  const int base = t * 20;
  int local[20];
  int s = 0;
#pragma unroll
  for (int i = 0; i < 20; ++i) {
    int idx = base + i;
    int v = (idx < N_NODES) ? cnt[idx] : 0;
    local[i] = s;
    s += v;
  }
  int x = s;
#pragma unroll
  for (int off = 1; off < 64; off <<= 1) {
    int v = __shfl_up(x, off);
    if (lane >= off) x += v;
  }
  if (lane == 63) wsum[wid] = x;
  __syncthreads();
  if (t < 16) {
    int y = wsum[t];
#pragma unroll
    for (int off = 1; off < 16; off <<= 1) {
      int v = __shfl_up(y, off);
      if (t >= off) y += v;
    }
    wsum[t] = y;
  }
  __syncthreads();
  const int woff = (wid > 0) ? wsum[wid - 1] : 0;
  const int incl = x + woff;
  const int excl = incl - s;
#pragma unroll
  for (int i = 0; i < 20; ++i) {
    int idx = base + i;
    if (idx < N_NODES) { int p = excl + local[i]; rptr[idx] = p; cur[idx] = p; }
  }
  if (t == 1023) rptr[N_NODES] = incl;
}

// ---------------------------------------------------------------- scatter + NW1 (fused)
__global__ __launch_bounds__(256, 4) void scatnw1_kernel(
    const int* __restrict__ src, const int* __restrict__ dst,
    int* __restrict__ cur, int* __restrict__ perm, int* __restrict__ sdP,
    const float* __restrict__ node, const unsigned short* __restrict__ P1m,
    const float* __restrict__ b1m, unsigned short* __restrict__ NW1) {
  __shared__ unsigned short tA[NBLK * 256];
  const int tid = threadIdx.x;
  if (blockIdx.x < 1250) {
    int e = blockIdx.x * 256 + tid;
    int d = dst[e];
    int pos = atomicAdd(&cur[d], 1);
    perm[pos] = e;
    sdP[pos] = (src[e] & 0xFFFF) | (d << 16);
    return;
  }
  const int n0 = (blockIdx.x - 1250) * NBLK;
  {
    const int r = tid >> 3;
    const int cs = (tid & 7) * 32;
    const float* np = node + (size_t)(n0 + r) * 256 + cs;
#pragma unroll
    for (int i = 0; i < 4; ++i) {
      float4 a = *(const float4*)(np + i * 8);
      float4 b = *(const float4*)(np + i * 8 + 4);
      uint4 p;
      p.x = pk2(a.x, a.y); p.y = pk2(a.z, a.w);
      p.z = pk2(b.x, b.y); p.w = pk2(b.z, b.w);
      *(uint4*)((char*)tA + SWZ(r, r * 512 + (cs + i * 8) * 2)) = p;
    }
  }
  __syncthreads();
  const int w = tid >> 6, l = tid & 63, lr = l & 15, lh = l >> 4;
  f32x4 acc[2][4];
#pragma unroll
  for (int r4 = 0; r4 < 2; ++r4)
#pragma unroll
    for (int c = 0; c < 4; ++c) acc[r4][c] = f32x4{0.f, 0.f, 0.f, 0.f};
#pragma unroll
  for (int t = 0; t < 8; ++t) {
    const int row0 = lr, row1 = 16 + lr;
    short8 af0 = *(const short8*)((const char*)tA + SWZ(row0, row0 * 512 + t * 64 + lh * 16));
    short8 af1 = *(const short8*)((const char*)tA + SWZ(row1, row1 * 512 + t * 64 + lh * 16));
#pragma unroll
    for (int c = 0; c < 4; ++c) {
      short8 bfr = *(const short8*)(P1m + (size_t)(((w * 4 + c) * 8 + t) * 512 + l * 8));
      acc[0][c] = __builtin_amdgcn_mfma_f32_16x16x32_bf16(af0, bfr, acc[0][c], 0, 0, 0);
      acc[1][c] = __builtin_amdgcn_mfma_f32_16x16x32_bf16(af1, bfr, acc[1][c], 0, 0, 0);
    }
  }
#pragma unroll
  for (int r4 = 0; r4 < 2; ++r4)
#pragma unroll
    for (int c = 0; c < 4; ++c) {
      int col = w * 64 + c * 16 + lr;
      float bb = b1m[col];
#pragma unroll
      for (int j = 0; j < 4; ++j) {
        int row = r4 * 16 + lh * 4 + j;
        NW1[(size_t)(n0 + row) * 256 + col] = f2bf(acc[r4][c][j] + bb);
      }
    }
}

// ---------------------------------------------------------------- edge kernel
// ROUND-16 PROVEN VERSION (195us) with launch_bounds(512,8) as the single
// change (VGPR 36 << 64 cap; LDS 33KB -> 4 blocks/CU possible; the (512,7)
// hint measured only 65% occupancy while round-8's (512,8) shape hit 79%).
// Structure: stage eemb -> barrier -> NW1 prefetch (srcS via LDS, hidden
// under MFMA) -> MFMA -> +NW1, gelu -> ballot/shfl segmented reduction ->
// all-atomic coalesced flush. Round-17 lesson: do NOT front-load the NW1
// gathers before the barrier-feeding staging loads (+13us).
__global__ __launch_bounds__(512, 8) void edge_kernel(
    const float* __restrict__ eemb,
    const int* __restrict__ perm, const int* __restrict__ sdP,
    const unsigned short* __restrict__ P1m, const unsigned short* __restrict__ NW1,
    float* __restrict__ S) {
  __shared__ unsigned short tA[EBLK * 256];   // 32 KB
  __shared__ int dstS[EBLK], srcS[EBLK];
  const int tid = threadIdx.x;
  const int e0 = blockIdx.x * EBLK;
  {
    const int r = tid >> 3;            // row 0..63, 8 threads/row
    const int cs = (tid & 7) * 32;     // 32 cols per thread
    if ((tid & 7) == 0) {
      int sd = sdP[e0 + r];            // coalesced, independent of perm
      srcS[r] = sd & 0xFFFF;
      dstS[r] = sd >> 16;
    }
    const int e = perm[e0 + r];
    const float* ep = eemb + (size_t)e * 256 + cs;
#pragma unroll
    for (int i = 0; i < 4; ++i) {
      float4 a = *(const float4*)(ep + i * 8);
      float4 b = *(const float4*)(ep + i * 8 + 4);
      uint4 p;
      p.x = pk2(a.x, a.y); p.y = pk2(a.z, a.w);
      p.z = pk2(b.x, b.y); p.w = pk2(b.z, b.w);
      *(uint4*)((char*)tA + SWZ(r, r * 512 + (cs + i * 8) * 2)) = p;
    }
  }
  __syncthreads();  // the only barrier

  const int w = tid >> 6, l = tid & 63;   // 8 waves, each owns cols [w*32, w*32+32)
  const int lr = l & 15, lh = l >> 4;
  const int colbase = w * 32 + lr;

  // prefetch NW1 gather values (independent of LDS reads below; hides under MFMA)
  unsigned short nw0[4][4], nw1[4][4];
#pragma unroll
  for (int r4 = 0; r4 < 4; ++r4)
#pragma unroll
    for (int j = 0; j < 4; ++j) {
      int row = r4 * 16 + lh * 4 + j;
      const unsigned short* nwp = NW1 + (size_t)srcS[row] * 256 + colbase;
      nw0[r4][j] = nwp[0];
      nw1[r4][j] = nwp[16];
    }

  f32x4 acc[4][2];
#pragma unroll
  for (int r4 = 0; r4 < 4; ++r4)
#pragma unroll
    for (int c = 0; c < 2; ++c) acc[r4][c] = f32x4{0.f, 0.f, 0.f, 0.f};
#pragma unroll
  for (int kt = 0; kt < 8; ++kt) {
    short8 af[4];
#pragma unroll
    for (int r4 = 0; r4 < 4; ++r4) {
      int row = r4 * 16 + lr;
      af[r4] = *(const short8*)((const char*)tA + SWZ(row, row * 512 + kt * 64 + lh * 16));
    }
#pragma unroll
    for (int c = 0; c < 2; ++c) {
      short8 bfr = *(const short8*)(P1m + (size_t)(((w * 2 + c) * 8 + kt) * 512 + l * 8));
#pragma unroll
      for (int r4 = 0; r4 < 4; ++r4)
        acc[r4][c] = __builtin_amdgcn_mfma_f32_16x16x32_bf16(af[r4], bfr, acc[r4][c], 0, 0, 0);
    }
  }

  // epilogue: + NW1[src], gelu (f32 kept to the atomic)
#pragma unroll
  for (int r4 = 0; r4 < 4; ++r4)
#pragma unroll
    for (int j = 0; j < 4; ++j) {
      acc[r4][0][j] = gelu_f(acc[r4][0][j] + bf2f(nw0[r4][j]));
      acc[r4][1][j] = gelu_f(acc[r4][1][j] + bf2f(nw1[r4][j]));
    }

  // segment structure over 64 sorted rows: row i starts a segment iff dst changes
  const int dv = dstS[l];
  const int pv = __shfl(dv, (l - 1) & 63);
  const bool bflag = (l == 0) || (dv != pv);
  const unsigned long long mask = __ballot(bflag);
  const int nseg = __popcll(mask);
  int sid[4][4];
#pragma unroll
  for (int r4 = 0; r4 < 4; ++r4)
#pragma unroll
    for (int j = 0; j < 4; ++j) {
      int row = r4 * 16 + lh * 4 + j;
      sid[r4][j] = __popcll(mask & ((2ULL << row) - 1)) - 1;
    }
  unsigned long long rem = mask;
  for (int s = 0; s < nseg; ++s) {
    const int rowf = __builtin_ctzll(rem);
    rem &= rem - 1;
    const int dseg = __shfl(dv, rowf);
    float p0 = 0.f, p1 = 0.f;
#pragma unroll
    for (int r4 = 0; r4 < 4; ++r4)
#pragma unroll
      for (int j = 0; j < 4; ++j) {
        bool m = (sid[r4][j] == s);
        p0 += m ? acc[r4][0][j] : 0.f;
        p1 += m ? acc[r4][1][j] : 0.f;
      }
    p0 += __shfl_xor(p0, 16); p0 += __shfl_xor(p0, 32);
    p1 += __shfl_xor(p1, 16); p1 += __shfl_xor(p1, 32);
    if (lh == 0) {
      float* Sp = S + (size_t)dseg * 256 + colbase;
      atomicAdd(Sp, p0);
      atomicAdd(Sp + 16, p1);
    }
  }
}

// ---------------------------------------------------------------- node kernel
// ROUND-10/14/16 PROVEN VERSION (tH 16KB).
__global__ __launch_bounds__(256, 4) void node_kernel(
    const float* __restrict__ node, const float* __restrict__ S, const int* __restrict__ rptr,
    const unsigned short* __restrict__ P2m, const float* __restrict__ b2m,
    const unsigned short* __restrict__ P1u, const float* __restrict__ b1u,
    const unsigned short* __restrict__ P2u, const float* __restrict__ b2u,
    const float* __restrict__ gamma, const float* __restrict__ beta,
    float* __restrict__ out) {
  __shared__ unsigned short tAB[2][NBLK * 256];  // 32KB; later fp32 U 32KB
  __shared__ unsigned short tH[NBLK * 256];      // 16KB (one 256-col half of H)
  __shared__ float fmu[NBLK], frs[NBLK], fflag[NBLK];
  float* tU = (float*)tAB;
  const int tid = threadIdx.x;
  const int n0 = blockIdx.x * NBLK;
  const int r = tid >> 3;
  const int cs = (tid & 7) * 32;
  const int n = n0 + r;  // 625*32 == 20000: always valid
  {
    int dgi = rptr[n + 1] - rptr[n];
    float rec = 1.0f / fmaxf((float)dgi, 1.0f);
    if ((tid & 7) == 0) fflag[r] = (dgi > 0) ? 1.0f : 0.0f;
    const float* sp = S + (size_t)n * 256 + cs;
#pragma unroll
    for (int i = 0; i < 4; ++i) {
      float4 a = *(const float4*)(sp + i * 8);
      float4 b = *(const float4*)(sp + i * 8 + 4);
      uint4 p;
      p.x = pk2(a.x * rec, a.y * rec);
      p.y = pk2(a.z * rec, a.w * rec);
      p.z = pk2(b.x * rec, b.y * rec);
      p.w = pk2(b.z * rec, b.w * rec);
      *(uint4*)((char*)tAB[0] + SWZ(r, r * 512 + (cs + i * 8) * 2)) = p;
    }
  }
  __syncthreads();
  const int w = tid >> 6, l = tid & 63, lr = l & 15, lh = l >> 4;

  // ---- GEMM1: agg = A2 @ W2m + flag*b2m -> tAB[1] (bf16)
  {
    f32x4 acc[2][4];
#pragma unroll
    for (int r4 = 0; r4 < 2; ++r4)
#pragma unroll
      for (int c = 0; c < 4; ++c) acc[r4][c] = f32x4{0.f, 0.f, 0.f, 0.f};
#pragma unroll
    for (int t = 0; t < 8; ++t) {
      const int row0 = lr, row1 = 16 + lr;
      short8 af0 = *(const short8*)((const char*)tAB[0] + SWZ(row0, row0 * 512 + t * 64 + lh * 16));
      short8 af1 = *(const short8*)((const char*)tAB[0] + SWZ(row1, row1 * 512 + t * 64 + lh * 16));
#pragma unroll
      for (int c = 0; c < 4; ++c) {
        short8 bfr = *(const short8*)(P2m + (size_t)(((w * 4 + c) * 8 + t) * 512 + l * 8));
        acc[0][c] = __builtin_amdgcn_mfma_f32_16x16x32_bf16(af0, bfr, acc[0][c], 0, 0, 0);
        acc[1][c] = __builtin_amdgcn_mfma_f32_16x16x32_bf16(af1, bfr, acc[1][c], 0, 0, 0);
      }
    }
#pragma unroll
    for (int r4 = 0; r4 < 2; ++r4)
#pragma unroll
      for (int c = 0; c < 4; ++c) {
        int col = w * 64 + c * 16 + lr;
        float bm = b2m[col];
#pragma unroll
        for (int j = 0; j < 4; ++j) {
          int row = r4 * 16 + lh * 4 + j;
          float v = acc[r4][c][j] + fflag[row] * bm;
          *(unsigned short*)((char*)tAB[1] + SWZ(row, row * 512 + col * 2)) = f2bf(v);
        }
      }
  }
  __syncthreads();

  // ---- halves: GEMM2 (Hh = gelu(agg@W1u_h+b1u_h)) + GEMM3 partial (U += Hh@W2u_h)
  f32x4 acc3[2][4];
#pragma unroll
  for (int c = 0; c < 4; ++c) {
    float bb = b2u[w * 64 + c * 16 + lr];
    acc3[0][c] = f32x4{bb, bb, bb, bb};
    acc3[1][c] = f32x4{bb, bb, bb, bb};
  }
#pragma unroll
  for (int half = 0; half < 2; ++half) {
    {
      f32x4 acc[2][4];
#pragma unroll
      for (int r4 = 0; r4 < 2; ++r4)
#pragma unroll
        for (int c = 0; c < 4; ++c) acc[r4][c] = f32x4{0.f, 0.f, 0.f, 0.f};
#pragma unroll
      for (int t = 0; t < 8; ++t) {
        const int row0 = lr, row1 = 16 + lr;
        short8 af0 = *(const short8*)((const char*)tAB[1] + SWZ(row0, row0 * 512 + t * 64 + lh * 16));
        short8 af1 = *(const short8*)((const char*)tAB[1] + SWZ(row1, row1 * 512 + t * 64 + lh * 16));
#pragma unroll
        for (int c = 0; c < 4; ++c) {
          short8 bfr = *(const short8*)(P1u + (size_t)(((half * 16 + w * 4 + c) * 8 + t) * 512 + l * 8));
          acc[0][c] = __builtin_amdgcn_mfma_f32_16x16x32_bf16(af0, bfr, acc[0][c], 0, 0, 0);
          acc[1][c] = __builtin_amdgcn_mfma_f32_16x16x32_bf16(af1, bfr, acc[1][c], 0, 0, 0);
        }
      }
#pragma unroll
      for (int r4 = 0; r4 < 2; ++r4)
#pragma unroll
        for (int c = 0; c < 4; ++c) {
          int col = w * 64 + c * 16 + lr;  // within half
          float b1 = b1u[half * 256 + col];
#pragma unroll
          for (int j = 0; j < 4; ++j) {
            int row = r4 * 16 + lh * 4 + j;
            float v = gelu_f(acc[r4][c][j] + b1);
            *(unsigned short*)((char*)tH + SWZ(row, row * 512 + col * 2)) = f2bf(v);
          }
        }
    }
    __syncthreads();
    {
#pragma unroll
      for (int tt = 0; tt < 8; ++tt) {
        const int row0 = lr, row1 = 16 + lr;
        short8 af0 = *(const short8*)((const char*)tH + SWZ(row0, row0 * 512 + tt * 64 + lh * 16));
        short8 af1 = *(const short8*)((const char*)tH + SWZ(row1, row1 * 512 + tt * 64 + lh * 16));
#pragma unroll
        for (int c = 0; c < 4; ++c) {
          short8 bfr = *(const short8*)(P2u + (size_t)(((w * 4 + c) * 16 + half * 8 + tt) * 512 + l * 8));
          acc3[0][c] = __builtin_amdgcn_mfma_f32_16x16x32_bf16(af0, bfr, acc3[0][c], 0, 0, 0);
          acc3[1][c] = __builtin_amdgcn_mfma_f32_16x16x32_bf16(af1, bfr, acc3[1][c], 0, 0, 0);
        }
      }
    }
    __syncthreads();
  }

  // ---- write U fp32 (tAB fully dead by the post-Hh barrier)
#pragma unroll
  for (int r4 = 0; r4 < 2; ++r4)
#pragma unroll
    for (int c = 0; c < 4; ++c) {
      int col = w * 64 + c * 16 + lr;
#pragma unroll
      for (int j = 0; j < 4; ++j) {
        int row = r4 * 16 + lh * 4 + j;
        *(float*)((char*)tU + SWZU(row * 1024 + col * 4)) = acc3[r4][c][j];
      }
    }
  __syncthreads();

  // ---- residual + LayerNorm stats (8 threads per row)
  {
    float sum = 0.f, sq = 0.f;
#pragma unroll
    for (int i = 0; i < 8; ++i) {
      int byte = SWZU(r * 1024 + (cs + i * 4) * 4);
      float4 v = *(float4*)((char*)tU + byte);
      const float4 nb = *(const float4*)(node + (size_t)n * 256 + cs + i * 4);
      v.x += nb.x; v.y += nb.y; v.z += nb.z; v.w += nb.w;
      *(float4*)((char*)tU + byte) = v;
      sum += v.x + v.y + v.z + v.w;
      sq += v.x * v.x + v.y * v.y + v.z * v.z + v.w * v.w;
    }
    sum += __shfl_xor(sum, 1); sum += __shfl_xor(sum, 2); sum += __shfl_xor(sum, 4);
    sq  += __shfl_xor(sq, 1);  sq  += __shfl_xor(sq, 2);  sq  += __shfl_xor(sq, 4);
    if ((tid & 7) == 0) {
      float mu = sum * (1.0f / 256.0f);
      fmu[r] = mu;
      frs[r] = rsqrtf(fmaxf(sq * (1.0f / 256.0f) - mu * mu, 0.0f) + 1e-5f);
    }
  }
  __syncthreads();
#pragma unroll
  for (int i = 0; i < 8; ++i) {
    int f4 = i * 256 + tid;
    int row = f4 >> 6;
    int c4 = f4 & 63;
    float4 v = *(float4*)((char*)tU + SWZU(row * 1024 + c4 * 16));
    float mu = fmu[row], rs = frs[row];
    float4 g  = *(const float4*)(gamma + c4 * 4);
    float4 bt = *(const float4*)(beta + c4 * 4);
    float4 o;
    o.x = (v.x - mu) * rs * g.x + bt.x;
    o.y = (v.y - mu) * rs * g.y + bt.y;
    o.z = (v.z - mu) * rs * g.z + bt.z;
    o.w = (v.w - mu) * rs * g.w + bt.w;
    *(float4*)(out + (size_t)(n0 + row) * 256 + c4 * 4) = o;
  }
}

// ---------------------------------------------------------------- launch
extern "C" void kernel_launch(void* const* d_in, const int* in_sizes, int n_in,
                              void* d_out, int out_size, void* d_ws, size_t ws_size,
                              hipStream_t stream) {
  const float* node = (const float*)d_in[0];
  const int* eidx = (const int*)d_in[1];   // harness delivers integer inputs as int32
  const float* eemb = (const float*)d_in[2];
  const float* W1m = (const float*)d_in[3];
  const float* b1m = (const float*)d_in[4];
  const float* W2m = (const float*)d_in[5];
  const float* b2m = (const float*)d_in[6];
  const float* W1u = (const float*)d_in[7];
  const float* b1u = (const float*)d_in[8];
  const float* W2u = (const float*)d_in[9];
  const float* b2u = (const float*)d_in[10];
  const float* gamma = (const float*)d_in[11];
  const float* beta = (const float*)d_in[12];
  float* out = (float*)d_out;  // doubles as the scatter accumulator S [N,256] f32

  char* ws = (char*)d_ws;
  int* cnt  = (int*)ws;                                   // 80000 B
  int* rptr = (int*)(ws + 81920);                         // 80004 B
  int* cur  = (int*)(ws + 163840);                        // 80000 B
  int* perm = (int*)(ws + 245760);                        // 1280000 B
  unsigned short* P1m = (unsigned short*)(ws + 1525760);  // 131072 B
  unsigned short* P2m = (unsigned short*)(ws + 1656832);  // 131072 B
  unsigned short* P1u = (unsigned short*)(ws + 1787904);  // 262144 B
  unsigned short* P2u = (unsigned short*)(ws + 2050048);  // 262144 B
  unsigned short* NW1 = (unsigned short*)(ws + 2312192);  // 10240000 B (N x 256 bf16)
  int* sdP = (int*)(ws + 12552192);                       // 1280000 B (src|dst<<16, sorted)
  const int* src = eidx;
  const int* dst = eidx + N_EDGES;

  hipMemsetAsync(out, 0, (size_t)N_NODES * 256 * 4, stream);  // S = 0
  hipMemsetAsync(cnt, 0, (size_t)N_NODES * 4, stream);        // cnt = 0
  packhist_kernel<<<1536 + 1250, 256, 0, stream>>>(W1m, W2m, W1u, W2u,
                                                   P1m, P2m, P1u, P2u, dst, cnt);
  scan_kernel<<<1, 1024, 0, stream>>>(cnt, rptr, cur);
  scatnw1_kernel<<<1250 + 625, 256, 0, stream>>>(src, dst, cur, perm, sdP,
                                                 node, P1m, b1m, NW1);
  edge_kernel<<<N_EDGES / EBLK, 512, 0, stream>>>(eemb, perm, sdP, P1m, NW1, out);
  node_kernel<<<N_NODES / NBLK, 256, 0, stream>>>(node, out, rptr, P2m, b2m,
                                                  P1u, b1u, P2u, b2u, gamma, beta, out);
}

// Round 19
// 309.675 us; speedup vs baseline: 1.2401x; 1.2401x over previous
//
#include <hip/hip_runtime.h>
#include <hip/hip_bf16.h>

#define N_NODES 20000
#define N_EDGES 320000
#define EBLK 64
#define NBLK 32

typedef __attribute__((ext_vector_type(8))) short short8;
typedef __attribute__((ext_vector_type(4))) float f32x4;

static __device__ __forceinline__ unsigned short f2bf(float f) {
  __hip_bfloat16 h = __float2bfloat16(f);
  union { __hip_bfloat16 h; unsigned short u; } cv; cv.h = h; return cv.u;
}

static __device__ __forceinline__ float bf2f(unsigned short u) {
  union { unsigned int u; float f; } cv; cv.u = ((unsigned int)u) << 16; return cv.f;
}

static __device__ __forceinline__ unsigned int pk2(float a, float b) {
  return (unsigned int)f2bf(a) | ((unsigned int)f2bf(b) << 16);
}

// tanh-form GELU via one v_exp_f32; max |err| vs exact-erf ~3e-3 (margin 3x+).
static __device__ __forceinline__ float gelu_f(float x) {
  float z = x * (2.3022082f + 0.1029432f * x * x);  // pre-scaled by log2(e)
  z = fminf(fmaxf(z, -30.0f), 30.0f);
  float t = exp2f(z);
  return x * t * __frcp_rn(1.0f + t);
}

// XOR swizzle for bf16 tiles (16B granule spread across rows)
#define SWZ(row, byteoff) ((byteoff) ^ (((row) & 7) << 4))
// fp32 U tile swizzle keyed off address bits
#define SWZU(b) ((b) ^ ((((b) >> 8) & 7) << 4))

// ---------------------------------------------------------------- pack + hist (fused)
__global__ void packhist_kernel(const float* __restrict__ W1m, const float* __restrict__ W2m,
                                const float* __restrict__ W1u, const float* __restrict__ W2u,
                                unsigned short* __restrict__ P1m, unsigned short* __restrict__ P2m,
                                unsigned short* __restrict__ P1u, unsigned short* __restrict__ P2u,
                                const int* __restrict__ dst, int* __restrict__ cnt) {
  if (blockIdx.x >= 1536) {
    int e = (blockIdx.x - 1536) * blockDim.x + threadIdx.x;
    atomicAdd(&cnt[dst[e]], 1);
    return;
  }
  int idx = blockIdx.x * blockDim.x + threadIdx.x;
  const float* W; unsigned short* P; int K, Nc, local;
  if (idx < 65536)        { W = W1m; P = P1m; K = 256; Nc = 256; local = idx; }
  else if (idx < 131072)  { W = W2m; P = P2m; K = 256; Nc = 256; local = idx - 65536; }
  else if (idx < 262144)  { W = W1u; P = P1u; K = 256; Nc = 512; local = idx - 131072; }
  else                    { W = W2u; P = P2u; K = 512; Nc = 256; local = idx - 262144; }
  int frag = local >> 9, wi = local & 511;
  int l = wi >> 3, i = wi & 7;
  int kf = K >> 5;
  int cf = frag / kf, t = frag % kf;
  int k = t * 32 + (l >> 4) * 8 + i;
  int n = cf * 16 + (l & 15);
  P[local] = f2bf(W[(size_t)k * Nc + n]);
}

// ---------------------------------------------------------------- prefix scan
__global__ __launch_bounds__(1024) void scan_kernel(const int* __restrict__ cnt,
                                                    int* __restrict__ rptr,
                                                    int* __restrict__ cur) {
  __shared__ int wsum[16];
  const int t = threadIdx.x;
  const int lane = t & 63, wid = t >> 6;
  const int base = t * 20;
  int local[20];
  int s = 0;
#pragma unroll
  for (int i = 0; i < 20; ++i) {
    int idx = base + i;
    int v = (idx < N_NODES) ? cnt[idx] : 0;
    local[i] = s;
    s += v;
  }
  int x = s;
#pragma unroll
  for (int off = 1; off < 64; off <<= 1) {
    int v = __shfl_up(x, off);
    if (lane >= off) x += v;
  }
  if (lane == 63) wsum[wid] = x;
  __syncthreads();
  if (t < 16) {
    int y = wsum[t];
#pragma unroll
    for (int off = 1; off < 16; off <<= 1) {
      int v = __shfl_up(y, off);
      if (t >= off) y += v;
    }
    wsum[t] = y;
  }
  __syncthreads();
  const int woff = (wid > 0) ? wsum[wid - 1] : 0;
  const int incl = x + woff;
  const int excl = incl - s;
#pragma unroll
  for (int i = 0; i < 20; ++i) {
    int idx = base + i;
    if (idx < N_NODES) { int p = excl + local[i]; rptr[idx] = p; cur[idx] = p; }
  }
  if (t == 1023) rptr[N_NODES] = incl;
}

// ---------------------------------------------------------------- scatter + NW1 (fused)
__global__ __launch_bounds__(256, 4) void scatnw1_kernel(
    const int* __restrict__ src, const int* __restrict__ dst,
    int* __restrict__ cur, int* __restrict__ perm, int* __restrict__ sdP,
    const float* __restrict__ node, const unsigned short* __restrict__ P1m,
    const float* __restrict__ b1m, unsigned short* __restrict__ NW1) {
  __shared__ unsigned short tA[NBLK * 256];
  const int tid = threadIdx.x;
  if (blockIdx.x < 1250) {
    int e = blockIdx.x * 256 + tid;
    int d = dst[e];
    int pos = atomicAdd(&cur[d], 1);
    perm[pos] = e;
    sdP[pos] = (src[e] & 0xFFFF) | (d << 16);
    return;
  }
  const int n0 = (blockIdx.x - 1250) * NBLK;
  {
    const int r = tid >> 3;
    const int cs = (tid & 7) * 32;
    const float* np = node + (size_t)(n0 + r) * 256 + cs;
#pragma unroll
    for (int i = 0; i < 4; ++i) {
      float4 a = *(const float4*)(np + i * 8);
      float4 b = *(const float4*)(np + i * 8 + 4);
      uint4 p;
      p.x = pk2(a.x, a.y); p.y = pk2(a.z, a.w);
      p.z = pk2(b.x, b.y); p.w = pk2(b.z, b.w);
      *(uint4*)((char*)tA + SWZ(r, r * 512 + (cs + i * 8) * 2)) = p;
    }
  }
  __syncthreads();
  const int w = tid >> 6, l = tid & 63, lr = l & 15, lh = l >> 4;
  f32x4 acc[2][4];
#pragma unroll
  for (int r4 = 0; r4 < 2; ++r4)
#pragma unroll
    for (int c = 0; c < 4; ++c) acc[r4][c] = f32x4{0.f, 0.f, 0.f, 0.f};
#pragma unroll
  for (int t = 0; t < 8; ++t) {
    const int row0 = lr, row1 = 16 + lr;
    short8 af0 = *(const short8*)((const char*)tA + SWZ(row0, row0 * 512 + t * 64 + lh * 16));
    short8 af1 = *(const short8*)((const char*)tA + SWZ(row1, row1 * 512 + t * 64 + lh * 16));
#pragma unroll
    for (int c = 0; c < 4; ++c) {
      short8 bfr = *(const short8*)(P1m + (size_t)(((w * 4 + c) * 8 + t) * 512 + l * 8));
      acc[0][c] = __builtin_amdgcn_mfma_f32_16x16x32_bf16(af0, bfr, acc[0][c], 0, 0, 0);
      acc[1][c] = __builtin_amdgcn_mfma_f32_16x16x32_bf16(af1, bfr, acc[1][c], 0, 0, 0);
    }
  }
#pragma unroll
  for (int r4 = 0; r4 < 2; ++r4)
#pragma unroll
    for (int c = 0; c < 4; ++c) {
      int col = w * 64 + c * 16 + lr;
      float bb = b1m[col];
#pragma unroll
      for (int j = 0; j < 4; ++j) {
        int row = r4 * 16 + lh * 4 + j;
        NW1[(size_t)(n0 + row) * 256 + col] = f2bf(acc[r4][c][j] + bb);
      }
    }
}

// ---------------------------------------------------------------- edge kernel
// ROUND-16 PROVEN VERSION (195us, total 310us). 64 dst-sorted edges/block,
// 8 waves, launch_bounds(512,7). Stage eemb -> barrier -> NW1 prefetch (srcS
// via LDS, hidden under MFMA) -> MFMA (T=eemb@W1m) -> +NW1, gelu ->
// ballot/shfl segmented reduction -> all-atomic coalesced flush.
// Locked-in lessons: (512,8) raises occupancy 65->82% but atomic interleaving
// from more in-flight blocks thrashes L2 write coalescing (WRITE 35->357MB,
// +80us). Pre-barrier NW1 prefetch delays barrier-feeding staging (+13us).
// Plain-store/LDS-slot/MFMA-indicator reductions all amplify memory traffic.
// 65% occupancy is the atomic-locality equilibrium, not slack.
__global__ __launch_bounds__(512, 7) void edge_kernel(
    const float* __restrict__ eemb,
    const int* __restrict__ perm, const int* __restrict__ sdP,
    const unsigned short* __restrict__ P1m, const unsigned short* __restrict__ NW1,
    float* __restrict__ S) {
  __shared__ unsigned short tA[EBLK * 256];   // 32 KB
  __shared__ int dstS[EBLK], srcS[EBLK];
  const int tid = threadIdx.x;
  const int e0 = blockIdx.x * EBLK;
  {
    const int r = tid >> 3;            // row 0..63, 8 threads/row
    const int cs = (tid & 7) * 32;     // 32 cols per thread
    if ((tid & 7) == 0) {
      int sd = sdP[e0 + r];            // coalesced, independent of perm
      srcS[r] = sd & 0xFFFF;
      dstS[r] = sd >> 16;
    }
    const int e = perm[e0 + r];
    const float* ep = eemb + (size_t)e * 256 + cs;
#pragma unroll
    for (int i = 0; i < 4; ++i) {
      float4 a = *(const float4*)(ep + i * 8);
      float4 b = *(const float4*)(ep + i * 8 + 4);
      uint4 p;
      p.x = pk2(a.x, a.y); p.y = pk2(a.z, a.w);
      p.z = pk2(b.x, b.y); p.w = pk2(b.z, b.w);
      *(uint4*)((char*)tA + SWZ(r, r * 512 + (cs + i * 8) * 2)) = p;
    }
  }
  __syncthreads();  // the only barrier

  const int w = tid >> 6, l = tid & 63;   // 8 waves, each owns cols [w*32, w*32+32)
  const int lr = l & 15, lh = l >> 4;
  const int colbase = w * 32 + lr;

  // prefetch NW1 gather values (independent of LDS reads below; hides under MFMA)
  unsigned short nw0[4][4], nw1[4][4];
#pragma unroll
  for (int r4 = 0; r4 < 4; ++r4)
#pragma unroll
    for (int j = 0; j < 4; ++j) {
      int row = r4 * 16 + lh * 4 + j;
      const unsigned short* nwp = NW1 + (size_t)srcS[row] * 256 + colbase;
      nw0[r4][j] = nwp[0];
      nw1[r4][j] = nwp[16];
    }

  f32x4 acc[4][2];
#pragma unroll
  for (int r4 = 0; r4 < 4; ++r4)
#pragma unroll
    for (int c = 0; c < 2; ++c) acc[r4][c] = f32x4{0.f, 0.f, 0.f, 0.f};
#pragma unroll
  for (int kt = 0; kt < 8; ++kt) {
    short8 af[4];
#pragma unroll
    for (int r4 = 0; r4 < 4; ++r4) {
      int row = r4 * 16 + lr;
      af[r4] = *(const short8*)((const char*)tA + SWZ(row, row * 512 + kt * 64 + lh * 16));
    }
#pragma unroll
    for (int c = 0; c < 2; ++c) {
      short8 bfr = *(const short8*)(P1m + (size_t)(((w * 2 + c) * 8 + kt) * 512 + l * 8));
#pragma unroll
      for (int r4 = 0; r4 < 4; ++r4)
        acc[r4][c] = __builtin_amdgcn_mfma_f32_16x16x32_bf16(af[r4], bfr, acc[r4][c], 0, 0, 0);
    }
  }

  // epilogue: + NW1[src], gelu (f32 kept to the atomic)
#pragma unroll
  for (int r4 = 0; r4 < 4; ++r4)
#pragma unroll
    for (int j = 0; j < 4; ++j) {
      acc[r4][0][j] = gelu_f(acc[r4][0][j] + bf2f(nw0[r4][j]));
      acc[r4][1][j] = gelu_f(acc[r4][1][j] + bf2f(nw1[r4][j]));
    }

  // segment structure over 64 sorted rows: row i starts a segment iff dst changes
  const int dv = dstS[l];
  const int pv = __shfl(dv, (l - 1) & 63);
  const bool bflag = (l == 0) || (dv != pv);
  const unsigned long long mask = __ballot(bflag);
  const int nseg = __popcll(mask);
  int sid[4][4];
#pragma unroll
  for (int r4 = 0; r4 < 4; ++r4)
#pragma unroll
    for (int j = 0; j < 4; ++j) {
      int row = r4 * 16 + lh * 4 + j;
      sid[r4][j] = __popcll(mask & ((2ULL << row) - 1)) - 1;
    }
  unsigned long long rem = mask;
  for (int s = 0; s < nseg; ++s) {
    const int rowf = __builtin_ctzll(rem);
    rem &= rem - 1;
    const int dseg = __shfl(dv, rowf);
    float p0 = 0.f, p1 = 0.f;
#pragma unroll
    for (int r4 = 0; r4 < 4; ++r4)
#pragma unroll
      for (int j = 0; j < 4; ++j) {
        bool m = (sid[r4][j] == s);
        p0 += m ? acc[r4][0][j] : 0.f;
        p1 += m ? acc[r4][1][j] : 0.f;
      }
    p0 += __shfl_xor(p0, 16); p0 += __shfl_xor(p0, 32);
    p1 += __shfl_xor(p1, 16); p1 += __shfl_xor(p1, 32);
    if (lh == 0) {
      float* Sp = S + (size_t)dseg * 256 + colbase;
      atomicAdd(Sp, p0);
      atomicAdd(Sp + 16, p1);
    }
  }
}

// ---------------------------------------------------------------- node kernel
// ROUND-10/14/16 PROVEN VERSION (tH 16KB).
__global__ __launch_bounds__(256, 4) void node_kernel(
    const float* __restrict__ node, const float* __restrict__ S, const int* __restrict__ rptr,
    const unsigned short* __restrict__ P2m, const float* __restrict__ b2m,
    const unsigned short* __restrict__ P1u, const float* __restrict__ b1u,
    const unsigned short* __restrict__ P2u, const float* __restrict__ b2u,
    const float* __restrict__ gamma, const float* __restrict__ beta,
    float* __restrict__ out) {
  __shared__ unsigned short tAB[2][NBLK * 256];  // 32KB; later fp32 U 32KB
  __shared__ unsigned short tH[NBLK * 256];      // 16KB (one 256-col half of H)
  __shared__ float fmu[NBLK], frs[NBLK], fflag[NBLK];
  float* tU = (float*)tAB;
  const int tid = threadIdx.x;
  const int n0 = blockIdx.x * NBLK;
  const int r = tid >> 3;
  const int cs = (tid & 7) * 32;
  const int n = n0 + r;  // 625*32 == 20000: always valid
  {
    int dgi = rptr[n + 1] - rptr[n];
    float rec = 1.0f / fmaxf((float)dgi, 1.0f);
    if ((tid & 7) == 0) fflag[r] = (dgi > 0) ? 1.0f : 0.0f;
    const float* sp = S + (size_t)n * 256 + cs;
#pragma unroll
    for (int i = 0; i < 4; ++i) {
      float4 a = *(const float4*)(sp + i * 8);
      float4 b = *(const float4*)(sp + i * 8 + 4);
      uint4 p;
      p.x = pk2(a.x * rec, a.y * rec);
      p.y = pk2(a.z * rec, a.w * rec);
      p.z = pk2(b.x * rec, b.y * rec);
      p.w = pk2(b.z * rec, b.w * rec);
      *(uint4*)((char*)tAB[0] + SWZ(r, r * 512 + (cs + i * 8) * 2)) = p;
    }
  }
  __syncthreads();
  const int w = tid >> 6, l = tid & 63, lr = l & 15, lh = l >> 4;

  // ---- GEMM1: agg = A2 @ W2m + flag*b2m -> tAB[1] (bf16)
  {
    f32x4 acc[2][4];
#pragma unroll
    for (int r4 = 0; r4 < 2; ++r4)
#pragma unroll
      for (int c = 0; c < 4; ++c) acc[r4][c] = f32x4{0.f, 0.f, 0.f, 0.f};
#pragma unroll
    for (int t = 0; t < 8; ++t) {
      const int row0 = lr, row1 = 16 + lr;
      short8 af0 = *(const short8*)((const char*)tAB[0] + SWZ(row0, row0 * 512 + t * 64 + lh * 16));
      short8 af1 = *(const short8*)((const char*)tAB[0] + SWZ(row1, row1 * 512 + t * 64 + lh * 16));
#pragma unroll
      for (int c = 0; c < 4; ++c) {
        short8 bfr = *(const short8*)(P2m + (size_t)(((w * 4 + c) * 8 + t) * 512 + l * 8));
        acc[0][c] = __builtin_amdgcn_mfma_f32_16x16x32_bf16(af0, bfr, acc[0][c], 0, 0, 0);
        acc[1][c] = __builtin_amdgcn_mfma_f32_16x16x32_bf16(af1, bfr, acc[1][c], 0, 0, 0);
      }
    }
#pragma unroll
    for (int r4 = 0; r4 < 2; ++r4)
#pragma unroll
      for (int c = 0; c < 4; ++c) {
        int col = w * 64 + c * 16 + lr;
        float bm = b2m[col];
#pragma unroll
        for (int j = 0; j < 4; ++j) {
          int row = r4 * 16 + lh * 4 + j;
          float v = acc[r4][c][j] + fflag[row] * bm;
          *(unsigned short*)((char*)tAB[1] + SWZ(row, row * 512 + col * 2)) = f2bf(v);
        }
      }
  }
  __syncthreads();

  // ---- halves: GEMM2 (Hh = gelu(agg@W1u_h+b1u_h)) + GEMM3 partial (U += Hh@W2u_h)
  f32x4 acc3[2][4];
#pragma unroll
  for (int c = 0; c < 4; ++c) {
    float bb = b2u[w * 64 + c * 16 + lr];
    acc3[0][c] = f32x4{bb, bb, bb, bb};
    acc3[1][c] = f32x4{bb, bb, bb, bb};
  }
#pragma unroll
  for (int half = 0; half < 2; ++half) {
    {
      f32x4 acc[2][4];
#pragma unroll
      for (int r4 = 0; r4 < 2; ++r4)
#pragma unroll
        for (int c = 0; c < 4; ++c) acc[r4][c] = f32x4{0.f, 0.f, 0.f, 0.f};
#pragma unroll
      for (int t = 0; t < 8; ++t) {
        const int row0 = lr, row1 = 16 + lr;
        short8 af0 = *(const short8*)((const char*)tAB[1] + SWZ(row0, row0 * 512 + t * 64 + lh * 16));
        short8 af1 = *(const short8*)((const char*)tAB[1] + SWZ(row1, row1 * 512 + t * 64 + lh * 16));
#pragma unroll
        for (int c = 0; c < 4; ++c) {
          short8 bfr = *(const short8*)(P1u + (size_t)(((half * 16 + w * 4 + c) * 8 + t) * 512 + l * 8));
          acc[0][c] = __builtin_amdgcn_mfma_f32_16x16x32_bf16(af0, bfr, acc[0][c], 0, 0, 0);
          acc[1][c] = __builtin_amdgcn_mfma_f32_16x16x32_bf16(af1, bfr, acc[1][c], 0, 0, 0);
        }
      }
#pragma unroll
      for (int r4 = 0; r4 < 2; ++r4)
#pragma unroll
        for (int c = 0; c < 4; ++c) {
          int col = w * 64 + c * 16 + lr;  // within half
          float b1 = b1u[half * 256 + col];
#pragma unroll
          for (int j = 0; j < 4; ++j) {
            int row = r4 * 16 + lh * 4 + j;
            float v = gelu_f(acc[r4][c][j] + b1);
            *(unsigned short*)((char*)tH + SWZ(row, row * 512 + col * 2)) = f2bf(v);
          }
        }
    }
    __syncthreads();
    {
#pragma unroll
      for (int tt = 0; tt < 8; ++tt) {
        const int row0 = lr, row1 = 16 + lr;
        short8 af0 = *(const short8*)((const char*)tH + SWZ(row0, row0 * 512 + tt * 64 + lh * 16));
        short8 af1 = *(const short8*)((const char*)tH + SWZ(row1, row1 * 512 + tt * 64 + lh * 16));
#pragma unroll
        for (int c = 0; c < 4; ++c) {
          short8 bfr = *(const short8*)(P2u + (size_t)(((w * 4 + c) * 16 + half * 8 + tt) * 512 + l * 8));
          acc3[0][c] = __builtin_amdgcn_mfma_f32_16x16x32_bf16(af0, bfr, acc3[0][c], 0, 0, 0);
          acc3[1][c] = __builtin_amdgcn_mfma_f32_16x16x32_bf16(af1, bfr, acc3[1][c], 0, 0, 0);
        }
      }
    }
    __syncthreads();
  }

  // ---- write U fp32 (tAB fully dead by the post-Hh barrier)
#pragma unroll
  for (int r4 = 0; r4 < 2; ++r4)
#pragma unroll
    for (int c = 0; c < 4; ++c) {
      int col = w * 64 + c * 16 + lr;
#pragma unroll
      for (int j = 0; j < 4; ++j) {
        int row = r4 * 16 + lh * 4 + j;
        *(float*)((char*)tU + SWZU(row * 1024 + col * 4)) = acc3[r4][c][j];
      }
    }
  __syncthreads();

  // ---- residual + LayerNorm stats (8 threads per row)
  {
    float sum = 0.f, sq = 0.f;
#pragma unroll
    for (int i = 0; i < 8; ++i) {
      int byte = SWZU(r * 1024 + (cs + i * 4) * 4);
      float4 v = *(float4*)((char*)tU + byte);
      const float4 nb = *(const float4*)(node + (size_t)n * 256 + cs + i * 4);
      v.x += nb.x; v.y += nb.y; v.z += nb.z; v.w += nb.w;
      *(float4*)((char*)tU + byte) = v;
      sum += v.x + v.y + v.z + v.w;
      sq += v.x * v.x + v.y * v.y + v.z * v.z + v.w * v.w;
    }
    sum += __shfl_xor(sum, 1); sum += __shfl_xor(sum, 2); sum += __shfl_xor(sum, 4);
    sq  += __shfl_xor(sq, 1);  sq  += __shfl_xor(sq, 2);  sq  += __shfl_xor(sq, 4);
    if ((tid & 7) == 0) {
      float mu = sum * (1.0f / 256.0f);
      fmu[r] = mu;
      frs[r] = rsqrtf(fmaxf(sq * (1.0f / 256.0f) - mu * mu, 0.0f) + 1e-5f);
    }
  }
  __syncthreads();
#pragma unroll
  for (int i = 0; i < 8; ++i) {
    int f4 = i * 256 + tid;
    int row = f4 >> 6;
    int c4 = f4 & 63;
    float4 v = *(float4*)((char*)tU + SWZU(row * 1024 + c4 * 16));
    float mu = fmu[row], rs = frs[row];
    float4 g  = *(const float4*)(gamma + c4 * 4);
    float4 bt = *(const float4*)(beta + c4 * 4);
    float4 o;
    o.x = (v.x - mu) * rs * g.x + bt.x;
    o.y = (v.y - mu) * rs * g.y + bt.y;
    o.z = (v.z - mu) * rs * g.z + bt.z;
    o.w = (v.w - mu) * rs * g.w + bt.w;
    *(float4*)(out + (size_t)(n0 + row) * 256 + c4 * 4) = o;
  }
}

// ---------------------------------------------------------------- launch
extern "C" void kernel_launch(void* const* d_in, const int* in_sizes, int n_in,
                              void* d_out, int out_size, void* d_ws, size_t ws_size,
                              hipStream_t stream) {
  const float* node = (const float*)d_in[0];
  const int* eidx = (const int*)d_in[1];   // harness delivers integer inputs as int32
  const float* eemb = (const float*)d_in[2];
  const float* W1m = (const float*)d_in[3];
  const float* b1m = (const float*)d_in[4];
  const float* W2m = (const float*)d_in[5];
  const float* b2m = (const float*)d_in[6];
  const float* W1u = (const float*)d_in[7];
  const float* b1u = (const float*)d_in[8];
  const float* W2u = (const float*)d_in[9];
  const float* b2u = (const float*)d_in[10];
  const float* gamma = (const float*)d_in[11];
  const float* beta = (const float*)d_in[12];
  float* out = (float*)d_out;  // doubles as the scatter accumulator S [N,256] f32

  char* ws = (char*)d_ws;
  int* cnt  = (int*)ws;                                   // 80000 B
  int* rptr = (int*)(ws + 81920);                         // 80004 B
  int* cur  = (int*)(ws + 163840);                        // 80000 B
  int* perm = (int*)(ws + 245760);                        // 1280000 B
  unsigned short* P1m = (unsigned short*)(ws + 1525760);  // 131072 B
  unsigned short* P2m = (unsigned short*)(ws + 1656832);  // 131072 B
  unsigned short* P1u = (unsigned short*)(ws + 1787904);  // 262144 B
  unsigned short* P2u = (unsigned short*)(ws + 2050048);  // 262144 B
  unsigned short* NW1 = (unsigned short*)(ws + 2312192);  // 10240000 B (N x 256 bf16)
  int* sdP = (int*)(ws + 12552192);                       // 1280000 B (src|dst<<16, sorted)
  const int* src = eidx;
  const int* dst = eidx + N_EDGES;

  hipMemsetAsync(out, 0, (size_t)N_NODES * 256 * 4, stream);  // S = 0
  hipMemsetAsync(cnt, 0, (size_t)N_NODES * 4, stream);        // cnt = 0
  packhist_kernel<<<1536 + 1250, 256, 0, stream>>>(W1m, W2m, W1u, W2u,
                                                   P1m, P2m, P1u, P2u, dst, cnt);
  scan_kernel<<<1, 1024, 0, stream>>>(cnt, rptr, cur);
  scatnw1_kernel<<<1250 + 625, 256, 0, stream>>>(src, dst, cur, perm, sdP,
                                                 node, P1m, b1m, NW1);
  edge_kernel<<<N_EDGES / EBLK, 512, 0, stream>>>(eemb, perm, sdP, P1m, NW1, out);
  node_kernel<<<N_NODES / NBLK, 256, 0, stream>>>(node, out, rptr, P2m, b2m,
                                                  P1u, b1u, P2u, b2u, gamma, beta, out);
}